// Round 7
// baseline (387.314 us; speedup 1.0000x reference)
//
#include <hip/hip_runtime.h>
#include <hip/hip_bf16.h>

// Round-7: BARRIER-FREE main kernel. Evidence r2-r6: per-CU tile throughput
// pinned ~137 cyc/edge regardless of bytes/grid/compute; the invariant was the
// per-tile __syncthreads coupling 8 waves to the gather tail. New design:
// each WAVE owns 32 edges x all 256 hidden. W1(+b1 aug, K=144) lives in LDS
// in fragment-swizzled order (one staging barrier total). Gather loads land
// directly in MFMA B-fragment layout (lane = edge, half = k-interleave) from a
// bf16 z copy (pre-pass, validated r4) -> no transpose, no barrier, no
// cross-wave dependency. fc2 in-lane + one shfl_xor(32).

#define N_NODES 100000
#define N_EDGES 500000
#define D_IN    128
#define D_HID   256
#define NTILES  (N_EDGES / 32)        // 15625 tiles of 32 edges
#define GRID    512                   // 2 blocks/CU (LDS-capped)
#define NWAVES  (GRID * 4)            // 2048 independent waves

typedef __bf16 bf16x8 __attribute__((ext_vector_type(8)));
typedef float  f32x16 __attribute__((ext_vector_type(16)));
typedef float  f32x4  __attribute__((ext_vector_type(4)));
typedef float  f32x2  __attribute__((ext_vector_type(2)));

union F4H { float4 v; f32x2 h[2]; };

__device__ __forceinline__ unsigned int pkbf(f32x2 q) {
    union { __hip_bfloat162 b; unsigned int u; } c;
    c.b = __float22bfloat162_rn(make_float2(q.x, q.y));   // RNE packed cvt
    return c.u;
}
__device__ __forceinline__ unsigned short f2bf(float f) {
    union { float f; unsigned int u; } c; c.f = f;
    return (unsigned short)((c.u + 0x7fffu + ((c.u >> 16) & 1u)) >> 16);
}
__device__ __forceinline__ float bflo(unsigned int w) {
    union { unsigned int u; float f; } c; c.u = w << 16; return c.f;
}
__device__ __forceinline__ float bfhi(unsigned int w) {
    union { unsigned int u; float f; } c; c.u = w & 0xffff0000u; return c.f;
}

// mish(x) = x * N/(N+2), N = E*(E+2), E = e^x  (exact identity)
__device__ __forceinline__ float mish_f(float x) {
    float xc  = fminf(x, 20.0f);
    float E   = __expf(xc);
    float num = E * (E + 2.0f);
    return x * num * __builtin_amdgcn_rcpf(num + 2.0f);
}

// ---- pre-pass: z (f32) -> bf16 (validated r4) ----
__global__ __launch_bounds__(256)
void z_to_bf16(const float* __restrict__ z, ushort* __restrict__ zb) {
    const int i = (blockIdx.x * 256 + threadIdx.x) * 8;   // 6250*256*8 exact
    F4H a{*reinterpret_cast<const float4*>(z + i)};
    F4H b{*reinterpret_cast<const float4*>(z + i + 4)};
    *reinterpret_cast<uint4*>(zb + i) =
        make_uint4(pkbf(a.h[0]), pkbf(a.h[1]), pkbf(b.h[0]), pkbf(b.h[1]));
}

__global__ __launch_bounds__(256, 2)
void edge_decoder_nobar(const ushort* __restrict__ zb,
                        const int*    __restrict__ edge,
                        const float*  __restrict__ W1,
                        const float*  __restrict__ b1,
                        const float*  __restrict__ W2,
                        const float*  __restrict__ b2,
                        float*        __restrict__ out) {
    // ldsA: fragment-swizzled W1aug. chunk id c = (mt*9+kk)*64 + lane, 16 B each.
    // chunk(mt,kk,lane) = W1[mt*32+(lane&31)][kk*16+(lane>>5)*8 .. +8] (bf16),
    // kk==8 holds the bias column: half==0 -> {b1[m],0..}, half==1 -> zeros.
    __shared__ ushort ldsA[8 * 9 * 64 * 8];   // 73,728 B
    __shared__ float  ldsW2[D_HID];           // 1 KB

    const int t    = threadIdx.x;
    const int wave = t >> 6;
    const int lane = t & 63;
    const int ecol = lane & 31;   // edge within tile; also MFMA m/n col
    const int half = lane >> 5;   // k-interleave

    // ---- one-time staging (the ONLY barrier in the kernel) ----
    ldsW2[t] = W2[t];   // t in [0,256)
    for (int c = t; c < 8 * 9 * 64; c += 256) {
        const int ln = c & 63, mtkk = c >> 6;
        const int mt = mtkk / 9, kk = mtkk - mt * 9;
        const int m = mt * 32 + (ln & 31), hf = ln >> 5;
        union { unsigned int u[4]; uint4 q; } o;
        if (kk < 8) {
            const float* wp = W1 + (size_t)m * D_IN + kk * 16 + hf * 8;
            F4H w0{*reinterpret_cast<const float4*>(wp)};
            F4H w1{*reinterpret_cast<const float4*>(wp + 4)};
            o.u[0] = pkbf(w0.h[0]); o.u[1] = pkbf(w0.h[1]);
            o.u[2] = pkbf(w1.h[0]); o.u[3] = pkbf(w1.h[1]);
        } else {
            o.u[0] = o.u[1] = o.u[2] = o.u[3] = 0u;
            if (hf == 0) o.u[0] = (unsigned int)f2bf(b1[m]);
        }
        *reinterpret_cast<uint4*>(&ldsA[c * 8]) = o.q;
    }
    __syncthreads();

    const float b2f = b2[0];

    // B-fragment for the bias column: B[k][n]=1 only at k=0 (half0, j=0)
    bf16x8 bfr8;
    {
        union { unsigned short s[8]; bf16x8 v; } u;
        #pragma unroll
        for (int j = 0; j < 8; ++j) u.s[j] = 0;
        if (half == 0) u.s[0] = 0x3F80;   // bf16 1.0
        bfr8 = u.v;
    }

    // ---- wave-independent edge-tile loop ----
    int T = blockIdx.x * 4 + wave;
    if (T >= NTILES) return;

    // prologue: indices + staged chunk loads for T; indices for T+NWAVES
    uint4 su[8], sv[8];
    {
        const int e = T * 32 + ecol;
        const int u = edge[e], v = edge[N_EDGES + e];
        const ushort* ru = zb + (size_t)u * D_IN + half * 8;
        const ushort* rv = zb + (size_t)v * D_IN + half * 8;
        #pragma unroll
        for (int kk = 0; kk < 8; ++kk) {
            su[kk] = *reinterpret_cast<const uint4*>(ru + kk * 16);
            sv[kk] = *reinterpret_cast<const uint4*>(rv + kk * 16);
        }
    }
    int eun = 0, evn = 0;
    {
        const int Tn = T + NWAVES;
        if (Tn < NTILES) {
            const int e = Tn * 32 + ecol;
            eun = edge[e]; evn = edge[N_EDGES + e];
        }
    }

    while (true) {
        // ---- build B-fragments for T (lane already holds exactly its chunks) ----
        bf16x8 bfr[8];
        #pragma unroll
        for (int kk = 0; kk < 8; ++kk) {
            unsigned int uu[4] = {su[kk].x, su[kk].y, su[kk].z, su[kk].w};
            unsigned int vv[4] = {sv[kk].x, sv[kk].y, sv[kk].z, sv[kk].w};
            union { unsigned int u[4]; bf16x8 v; } o;
            #pragma unroll
            for (int j = 0; j < 4; ++j) {
                f32x2 fu = {bflo(uu[j]), bfhi(uu[j])};
                f32x2 fv = {bflo(vv[j]), bfhi(vv[j])};
                o.u[j] = pkbf(fu * fv);
            }
            bfr[kk] = o.v;
        }

        // ---- issue next tile's chunk loads + indices 2 tiles ahead ----
        const int Tn = T + NWAVES;
        const bool hn = Tn < NTILES;
        if (hn) {
            const ushort* ru = zb + (size_t)eun * D_IN + half * 8;
            const ushort* rv = zb + (size_t)evn * D_IN + half * 8;
            #pragma unroll
            for (int kk = 0; kk < 8; ++kk) {
                su[kk] = *reinterpret_cast<const uint4*>(ru + kk * 16);
                sv[kk] = *reinterpret_cast<const uint4*>(rv + kk * 16);
            }
            const int Tnn = Tn + NWAVES;
            if (Tnn < NTILES) {
                const int e = Tnn * 32 + ecol;
                eun = edge[e]; evn = edge[N_EDGES + e];
            }
        }

        // ---- compute: 8 m-tiles x 9 kk MFMAs; epilogue per m-tile ----
        float s = 0.f;
        #pragma unroll
        for (int mt = 0; mt < 8; ++mt) {
            f32x16 acc = {0.f, 0.f, 0.f, 0.f, 0.f, 0.f, 0.f, 0.f,
                          0.f, 0.f, 0.f, 0.f, 0.f, 0.f, 0.f, 0.f};
            #pragma unroll
            for (int kk = 0; kk < 9; ++kk) {
                bf16x8 a = *reinterpret_cast<const bf16x8*>(
                    &ldsA[((mt * 9 + kk) * 64 + lane) * 8]);
                acc = __builtin_amdgcn_mfma_f32_32x32x16_bf16(
                    a, (kk < 8) ? bfr[kk] : bfr8, acc, 0, 0, 0);
            }
            // D: col=ecol(edge), row=(r&3)+8*(r>>2)+4*half (+mt*32). Bias inside.
            #pragma unroll
            for (int g = 0; g < 4; ++g) {
                f32x4 w = *reinterpret_cast<const f32x4*>(
                    &ldsW2[mt * 32 + g * 8 + half * 4]);
                #pragma unroll
                for (int j = 0; j < 4; ++j)
                    s = fmaf(mish_f(acc[g * 4 + j]), w[j], s);
            }
        }
        s += __shfl_xor(s, 32);               // combine the two k-halves
        if (lane < 32) {
            const float logit = s + b2f;
            out[T * 32 + ecol] = __builtin_amdgcn_rcpf(1.0f + __expf(-logit));
        }

        if (!hn) break;
        T = Tn;
    }
}

// ---------------- fallback (r6 kernel) if ws too small for zb ----------------
#define M_TILE  32
#define LDS_STRIDE 136
#define FGRID   1024

__global__ __launch_bounds__(512, 2)
void edge_decoder_fb(const float* __restrict__ z, const int* __restrict__ edge,
                     const float* __restrict__ W1, const float* __restrict__ b1,
                     const float* __restrict__ W2, const float* __restrict__ b2,
                     float* __restrict__ out) {
    __shared__ ushort xbuf[2][M_TILE * LDS_STRIDE];
    __shared__ float  lpart[2][8][M_TILE];
    const int t = threadIdx.x, wave = t >> 6, lane = t & 63;
    const int half = lane >> 5, col = lane & 31;
    bf16x8 afragW[8];
    {
        const float* wrow = W1 + (size_t)(wave * 32 + col) * D_IN;
        #pragma unroll
        for (int kk = 0; kk < 8; ++kk) {
            const float* wp = wrow + kk * 16 + half * 8;
            F4H w0{*reinterpret_cast<const float4*>(wp)};
            F4H w1{*reinterpret_cast<const float4*>(wp + 4)};
            union { unsigned int u[4]; bf16x8 v; } o;
            o.u[0] = pkbf(w0.h[0]); o.u[1] = pkbf(w0.h[1]);
            o.u[2] = pkbf(w1.h[0]); o.u[3] = pkbf(w1.h[1]);
            afragW[kk] = o.v;
        }
    }
    float b1c[16], w2f[16];
    #pragma unroll
    for (int r = 0; r < 16; ++r) {
        const int n = wave * 32 + (r & 3) + 8 * (r >> 2) + 4 * half;
        b1c[r] = b1[n]; w2f[r] = W2[n];
    }
    const float b2f = b2[0];
    const int s_slot = t >> 4, cch = t & 15;
    int tile = blockIdx.x;
    float4 a0, a1, c0, c1;
    {
        const int e = tile * M_TILE + s_slot;
        const int u = edge[e], v = edge[N_EDGES + e];
        const float* zu = z + (size_t)u * D_IN + cch * 8;
        const float* zv = z + (size_t)v * D_IN + cch * 8;
        a0 = *reinterpret_cast<const float4*>(zu); a1 = *reinterpret_cast<const float4*>(zu + 4);
        c0 = *reinterpret_cast<const float4*>(zv); c1 = *reinterpret_cast<const float4*>(zv + 4);
    }
    int u_n, v_n;
    {
        const int t1 = min(tile + FGRID, NTILES - 1);
        u_n = edge[t1 * M_TILE + s_slot]; v_n = edge[N_EDGES + t1 * M_TILE + s_slot];
    }
    int p = 0; bool have_prev = false; int prev_base = 0;
    for (; tile < NTILES; tile += FGRID) {
        {
            F4H A0{a0}, A1{a1}, C0{c0}, C1{c1};
            *reinterpret_cast<uint4*>(&xbuf[p][s_slot * LDS_STRIDE + cch * 8]) =
                make_uint4(pkbf(A0.h[0] * C0.h[0]), pkbf(A0.h[1] * C0.h[1]),
                           pkbf(A1.h[0] * C1.h[0]), pkbf(A1.h[1] * C1.h[1]));
        }
        __syncthreads();
        {
            const float* zu = z + (size_t)u_n * D_IN + cch * 8;
            const float* zv = z + (size_t)v_n * D_IN + cch * 8;
            a0 = *reinterpret_cast<const float4*>(zu); a1 = *reinterpret_cast<const float4*>(zu + 4);
            c0 = *reinterpret_cast<const float4*>(zv); c1 = *reinterpret_cast<const float4*>(zv + 4);
        }
        {
            const int t2 = min(tile + 2 * FGRID, NTILES - 1);
            u_n = edge[t2 * M_TILE + s_slot]; v_n = edge[N_EDGES + t2 * M_TILE + s_slot];
        }
        if (have_prev && t < M_TILE) {
            const int pp = p ^ 1; float logit = b2f;
            #pragma unroll
            for (int w = 0; w < 8; ++w) logit += lpart[pp][w][t];
            out[prev_base + t] = __builtin_amdgcn_rcpf(1.0f + __expf(-logit));
        }
        f32x16 acc;
        #pragma unroll
        for (int r = 0; r < 16; ++r) acc[r] = b1c[r];
        #pragma unroll
        for (int kk = 0; kk < 8; ++kk) {
            bf16x8 bx = *reinterpret_cast<const bf16x8*>(
                &xbuf[p][col * LDS_STRIDE + kk * 16 + half * 8]);
            acc = __builtin_amdgcn_mfma_f32_32x32x16_bf16(afragW[kk], bx, acc, 0, 0, 0);
        }
        float s = 0.f;
        #pragma unroll
        for (int r = 0; r < 16; ++r) s = fmaf(mish_f(acc[r]), w2f[r], s);
        s += __shfl_xor(s, 32);
        if (lane < 32) lpart[p][wave][col] = s;
        have_prev = true; prev_base = tile * M_TILE; p ^= 1;
    }
    __syncthreads();
    if (have_prev && t < M_TILE) {
        const int pp = p ^ 1; float logit = b2f;
        #pragma unroll
        for (int w = 0; w < 8; ++w) logit += lpart[pp][w][t];
        out[prev_base + t] = __builtin_amdgcn_rcpf(1.0f + __expf(-logit));
    }
}

extern "C" void kernel_launch(void* const* d_in, const int* in_sizes, int n_in,
                              void* d_out, int out_size, void* d_ws, size_t ws_size,
                              hipStream_t stream) {
    const float* z    = (const float*)d_in[0];
    const int*   edge = (const int*)d_in[1];
    const float* W1   = (const float*)d_in[2];
    const float* b1   = (const float*)d_in[3];
    const float* W2   = (const float*)d_in[4];
    const float* b2   = (const float*)d_in[5];
    float* out = (float*)d_out;

    const size_t zb_bytes = (size_t)N_NODES * D_IN * sizeof(ushort);  // 25.6 MB
    if (ws_size >= zb_bytes) {
        ushort* zb = (ushort*)d_ws;
        z_to_bf16<<<dim3((N_NODES * D_IN) / (256 * 8)), dim3(256), 0, stream>>>(z, zb);
        edge_decoder_nobar<<<dim3(GRID), dim3(256), 0, stream>>>(
            zb, edge, W1, b1, W2, b2, out);
    } else {
        edge_decoder_fb<<<dim3(FGRID), dim3(512), 0, stream>>>(
            z, edge, W1, b1, W2, b2, out);
    }
}

// Round 8
// 353.838 us; speedup vs baseline: 1.0946x; 1.0946x over previous
//
#include <hip/hip_runtime.h>
#include <hip/hip_bf16.h>

// Round-8: r7's barrier-free structure with register pressure FIXED.
// r7 spilled (WRITE_SIZE 176 MB): the 2-deep z-row prefetch held su[8]+sv[8]
// = 64 loop-carried VGPRs. r8: transient gather (loads consumed immediately
// into B-fragments), loop-carried state = 2 edge indices. Latency hiding via
// TLP: 512-thr blocks x grid 512 -> 2 blocks/CU (LDS 149.5/160 KB), 16
// waves/CU, VGPR cap 128 ((512,2) semantics proven spill-free in r6).
// Each WAVE owns a stream of 32-edge tiles x all 256 hidden. W1(+b1 as K=144
// aug column) staged once per block into LDS in fragment order; gather lands
// directly in MFMA B layout (lane=edge); fc2 in-lane + one shfl_xor(32).

#define N_NODES 100000
#define N_EDGES 500000
#define D_IN    128
#define D_HID   256
#define NTILES  (N_EDGES / 32)        // 15625 tiles of 32 edges
#define GRID    512
#define NSTREAM (GRID * 8)            // 4096 independent wave streams

typedef __bf16 bf16x8 __attribute__((ext_vector_type(8)));
typedef float  f32x16 __attribute__((ext_vector_type(16)));
typedef float  f32x4  __attribute__((ext_vector_type(4)));
typedef float  f32x2  __attribute__((ext_vector_type(2)));

union F4H { float4 v; f32x2 h[2]; };

__device__ __forceinline__ unsigned int pkbf(f32x2 q) {
    union { __hip_bfloat162 b; unsigned int u; } c;
    c.b = __float22bfloat162_rn(make_float2(q.x, q.y));   // RNE packed cvt
    return c.u;
}
__device__ __forceinline__ unsigned short f2bf(float f) {
    union { float f; unsigned int u; } c; c.f = f;
    return (unsigned short)((c.u + 0x7fffu + ((c.u >> 16) & 1u)) >> 16);
}
__device__ __forceinline__ float bflo(unsigned int w) {
    union { unsigned int u; float f; } c; c.u = w << 16; return c.f;
}
__device__ __forceinline__ float bfhi(unsigned int w) {
    union { unsigned int u; float f; } c; c.u = w & 0xffff0000u; return c.f;
}

// mish(x) = x * N/(N+2), N = E*(E+2), E = e^x  (exact identity)
__device__ __forceinline__ float mish_f(float x) {
    float xc  = fminf(x, 20.0f);
    float E   = __expf(xc);
    float num = E * (E + 2.0f);
    return x * num * __builtin_amdgcn_rcpf(num + 2.0f);
}

// ---- pre-pass: z (f32) -> bf16 (validated r4/r7) ----
__global__ __launch_bounds__(256)
void z_to_bf16(const float* __restrict__ z, ushort* __restrict__ zb) {
    const int i = (blockIdx.x * 256 + threadIdx.x) * 8;   // 6250*256*8 exact
    F4H a{*reinterpret_cast<const float4*>(z + i)};
    F4H b{*reinterpret_cast<const float4*>(z + i + 4)};
    *reinterpret_cast<uint4*>(zb + i) =
        make_uint4(pkbf(a.h[0]), pkbf(a.h[1]), pkbf(b.h[0]), pkbf(b.h[1]));
}

__global__ __launch_bounds__(512, 2)
void edge_decoder_nobar(const ushort* __restrict__ zb,
                        const int*    __restrict__ edge,
                        const float*  __restrict__ W1,
                        const float*  __restrict__ b1,
                        const float*  __restrict__ W2,
                        const float*  __restrict__ b2,
                        float*        __restrict__ out) {
    // ldsA chunk c=(mt*9+kk)*64+lane holds W1[mt*32+(lane&31)][kk*16+(lane>>5)*8..+8]
    // (bf16, 16 B); kk==8 is the bias column (b1 at k=0, else zeros).
    __shared__ ushort ldsA[8 * 9 * 64 * 8];   // 73,728 B
    __shared__ float  ldsW2[D_HID];           // 1 KB

    const int t    = threadIdx.x;
    const int wave = t >> 6;
    const int lane = t & 63;
    const int ecol = lane & 31;   // edge within tile = MFMA n col
    const int half = lane >> 5;   // k-interleave

    // ---- one-time staging (the ONLY barrier) ----
    if (t < D_HID) ldsW2[t] = W2[t];
    for (int c = t; c < 8 * 9 * 64; c += 512) {
        const int ln = c & 63, mtkk = c >> 6;
        const int mt = mtkk / 9, kk = mtkk - mt * 9;
        const int m = mt * 32 + (ln & 31), hf = ln >> 5;
        union { unsigned int u[4]; uint4 q; } o;
        if (kk < 8) {
            const float* wp = W1 + (size_t)m * D_IN + kk * 16 + hf * 8;
            F4H w0{*reinterpret_cast<const float4*>(wp)};
            F4H w1{*reinterpret_cast<const float4*>(wp + 4)};
            o.u[0] = pkbf(w0.h[0]); o.u[1] = pkbf(w0.h[1]);
            o.u[2] = pkbf(w1.h[0]); o.u[3] = pkbf(w1.h[1]);
        } else {
            o.u[0] = o.u[1] = o.u[2] = o.u[3] = 0u;
            if (hf == 0) o.u[0] = (unsigned int)f2bf(b1[m]);
        }
        *reinterpret_cast<uint4*>(&ldsA[c * 8]) = o.q;
    }
    __syncthreads();

    const float b2f = b2[0];

    // B-fragment for the bias column: B[k][n]=1 only at k=0 (half0, j=0)
    bf16x8 bfr8;
    {
        union { unsigned short s[8]; bf16x8 v; } u;
        #pragma unroll
        for (int j = 0; j < 8; ++j) u.s[j] = 0;
        if (half == 0) u.s[0] = 0x3F80;   // bf16 1.0
        bfr8 = u.v;
    }

    // ---- independent per-wave tile stream ----
    int T = blockIdx.x * 8 + wave;
    int eu = edge[T * 32 + ecol];
    int ev = edge[N_EDGES + T * 32 + ecol];

    while (true) {
        // ---- gather this tile's two z rows (transient), build B-fragments ----
        const ushort* ru = zb + (size_t)eu * D_IN + half * 8;
        const ushort* rv = zb + (size_t)ev * D_IN + half * 8;
        bf16x8 bfr[8];
        #pragma unroll
        for (int kk = 0; kk < 8; ++kk) {
            const uint4 a = *reinterpret_cast<const uint4*>(ru + kk * 16);
            const uint4 b = *reinterpret_cast<const uint4*>(rv + kk * 16);
            unsigned int uu[4] = {a.x, a.y, a.z, a.w};
            unsigned int vv[4] = {b.x, b.y, b.z, b.w};
            union { unsigned int u[4]; bf16x8 v; } o;
            #pragma unroll
            for (int j = 0; j < 4; ++j) {
                f32x2 fu = {bflo(uu[j]), bfhi(uu[j])};
                f32x2 fv = {bflo(vv[j]), bfhi(vv[j])};
                o.u[j] = pkbf(fu * fv);
            }
            bfr[kk] = o.v;
        }

        // ---- prefetch next tile's edge indices (2 regs, hides idx latency) ----
        const int Tn = T + NSTREAM;
        const bool hn = Tn < NTILES;
        int eun = eu, evn = ev;
        if (hn) {
            eun = edge[Tn * 32 + ecol];
            evn = edge[N_EDGES + Tn * 32 + ecol];
        }

        // ---- compute: 8 m-tiles x 9 kk MFMAs; fused epilogue ----
        float s = 0.f;
        #pragma unroll
        for (int mt = 0; mt < 8; ++mt) {
            f32x16 acc = {0.f, 0.f, 0.f, 0.f, 0.f, 0.f, 0.f, 0.f,
                          0.f, 0.f, 0.f, 0.f, 0.f, 0.f, 0.f, 0.f};
            #pragma unroll
            for (int kk = 0; kk < 9; ++kk) {
                bf16x8 a = *reinterpret_cast<const bf16x8*>(
                    &ldsA[((mt * 9 + kk) * 64 + lane) * 8]);
                acc = __builtin_amdgcn_mfma_f32_32x32x16_bf16(
                    a, (kk < 8) ? bfr[kk] : bfr8, acc, 0, 0, 0);
            }
            // D: col=ecol(edge), row=(r&3)+8*(r>>2)+4*half (+mt*32). Bias inside.
            #pragma unroll
            for (int g = 0; g < 4; ++g) {
                f32x4 w = *reinterpret_cast<const f32x4*>(
                    &ldsW2[mt * 32 + g * 8 + half * 4]);
                #pragma unroll
                for (int j = 0; j < 4; ++j)
                    s = fmaf(mish_f(acc[g * 4 + j]), w[j], s);
            }
        }
        s += __shfl_xor(s, 32);               // combine the two k-halves
        if (lane < 32) {
            const float logit = s + b2f;
            out[T * 32 + ecol] = __builtin_amdgcn_rcpf(1.0f + __expf(-logit));
        }

        if (!hn) break;
        T = Tn; eu = eun; ev = evn;
    }
}

// ---------------- fallback (r6 kernel) if ws too small for zb ----------------
#define M_TILE  32
#define LDS_STRIDE 136
#define FGRID   1024

__global__ __launch_bounds__(512, 2)
void edge_decoder_fb(const float* __restrict__ z, const int* __restrict__ edge,
                     const float* __restrict__ W1, const float* __restrict__ b1,
                     const float* __restrict__ W2, const float* __restrict__ b2,
                     float* __restrict__ out) {
    __shared__ ushort xbuf[2][M_TILE * LDS_STRIDE];
    __shared__ float  lpart[2][8][M_TILE];
    const int t = threadIdx.x, wave = t >> 6, lane = t & 63;
    const int half = lane >> 5, col = lane & 31;
    bf16x8 afragW[8];
    {
        const float* wrow = W1 + (size_t)(wave * 32 + col) * D_IN;
        #pragma unroll
        for (int kk = 0; kk < 8; ++kk) {
            const float* wp = wrow + kk * 16 + half * 8;
            F4H w0{*reinterpret_cast<const float4*>(wp)};
            F4H w1{*reinterpret_cast<const float4*>(wp + 4)};
            union { unsigned int u[4]; bf16x8 v; } o;
            o.u[0] = pkbf(w0.h[0]); o.u[1] = pkbf(w0.h[1]);
            o.u[2] = pkbf(w1.h[0]); o.u[3] = pkbf(w1.h[1]);
            afragW[kk] = o.v;
        }
    }
    float b1c[16], w2f[16];
    #pragma unroll
    for (int r = 0; r < 16; ++r) {
        const int n = wave * 32 + (r & 3) + 8 * (r >> 2) + 4 * half;
        b1c[r] = b1[n]; w2f[r] = W2[n];
    }
    const float b2f = b2[0];
    const int s_slot = t >> 4, cch = t & 15;
    int tile = blockIdx.x;
    float4 a0, a1, c0, c1;
    {
        const int e = tile * M_TILE + s_slot;
        const int u = edge[e], v = edge[N_EDGES + e];
        const float* zu = z + (size_t)u * D_IN + cch * 8;
        const float* zv = z + (size_t)v * D_IN + cch * 8;
        a0 = *reinterpret_cast<const float4*>(zu); a1 = *reinterpret_cast<const float4*>(zu + 4);
        c0 = *reinterpret_cast<const float4*>(zv); c1 = *reinterpret_cast<const float4*>(zv + 4);
    }
    int u_n, v_n;
    {
        const int t1 = min(tile + FGRID, NTILES - 1);
        u_n = edge[t1 * M_TILE + s_slot]; v_n = edge[N_EDGES + t1 * M_TILE + s_slot];
    }
    int p = 0; bool have_prev = false; int prev_base = 0;
    for (; tile < NTILES; tile += FGRID) {
        {
            F4H A0{a0}, A1{a1}, C0{c0}, C1{c1};
            *reinterpret_cast<uint4*>(&xbuf[p][s_slot * LDS_STRIDE + cch * 8]) =
                make_uint4(pkbf(A0.h[0] * C0.h[0]), pkbf(A0.h[1] * C0.h[1]),
                           pkbf(A1.h[0] * C1.h[0]), pkbf(A1.h[1] * C1.h[1]));
        }
        __syncthreads();
        {
            const float* zu = z + (size_t)u_n * D_IN + cch * 8;
            const float* zv = z + (size_t)v_n * D_IN + cch * 8;
            a0 = *reinterpret_cast<const float4*>(zu); a1 = *reinterpret_cast<const float4*>(zu + 4);
            c0 = *reinterpret_cast<const float4*>(zv); c1 = *reinterpret_cast<const float4*>(zv + 4);
        }
        {
            const int t2 = min(tile + 2 * FGRID, NTILES - 1);
            u_n = edge[t2 * M_TILE + s_slot]; v_n = edge[N_EDGES + t2 * M_TILE + s_slot];
        }
        if (have_prev && t < M_TILE) {
            const int pp = p ^ 1; float logit = b2f;
            #pragma unroll
            for (int w = 0; w < 8; ++w) logit += lpart[pp][w][t];
            out[prev_base + t] = __builtin_amdgcn_rcpf(1.0f + __expf(-logit));
        }
        f32x16 acc;
        #pragma unroll
        for (int r = 0; r < 16; ++r) acc[r] = b1c[r];
        #pragma unroll
        for (int kk = 0; kk < 8; ++kk) {
            bf16x8 bx = *reinterpret_cast<const bf16x8*>(
                &xbuf[p][col * LDS_STRIDE + kk * 16 + half * 8]);
            acc = __builtin_amdgcn_mfma_f32_32x32x16_bf16(afragW[kk], bx, acc, 0, 0, 0);
        }
        float s = 0.f;
        #pragma unroll
        for (int r = 0; r < 16; ++r) s = fmaf(mish_f(acc[r]), w2f[r], s);
        s += __shfl_xor(s, 32);
        if (lane < 32) lpart[p][wave][col] = s;
        have_prev = true; prev_base = tile * M_TILE; p ^= 1;
    }
    __syncthreads();
    if (have_prev && t < M_TILE) {
        const int pp = p ^ 1; float logit = b2f;
        #pragma unroll
        for (int w = 0; w < 8; ++w) logit += lpart[pp][w][t];
        out[prev_base + t] = __builtin_amdgcn_rcpf(1.0f + __expf(-logit));
    }
}

extern "C" void kernel_launch(void* const* d_in, const int* in_sizes, int n_in,
                              void* d_out, int out_size, void* d_ws, size_t ws_size,
                              hipStream_t stream) {
    const float* z    = (const float*)d_in[0];
    const int*   edge = (const int*)d_in[1];
    const float* W1   = (const float*)d_in[2];
    const float* b1   = (const float*)d_in[3];
    const float* W2   = (const float*)d_in[4];
    const float* b2   = (const float*)d_in[5];
    float* out = (float*)d_out;

    const size_t zb_bytes = (size_t)N_NODES * D_IN * sizeof(ushort);  // 25.6 MB
    if (ws_size >= zb_bytes) {
        ushort* zb = (ushort*)d_ws;
        z_to_bf16<<<dim3((N_NODES * D_IN) / (256 * 8)), dim3(256), 0, stream>>>(z, zb);
        edge_decoder_nobar<<<dim3(GRID), dim3(512), 0, stream>>>(
            zb, edge, W1, b1, W2, b2, out);
    } else {
        edge_decoder_fb<<<dim3(FGRID), dim3(512), 0, stream>>>(
            z, edge, W1, b1, W2, b2, out);
    }
}